// Round 3
// baseline (272.768 us; speedup 1.0000x reference)
//
#include <hip/hip_runtime.h>
#include <hip/hip_bf16.h>
#include <math.h>

// MambaBlock: 4-direction 2D selective scan + fuse + LN + SiLU
// B=2, H=W=128, D_MODEL=64, D_INNER=128, D_STATE=16, DT_RANK=4, D_CONV=4
//
// R14 = kernel fission. R12 (scan pipelining) and R13 (scan instr cut) were
// both NULL with VGPR pinned at 84 -> the fused k1 is structurally limited:
// 53KB LDS -> 3 blk/CU, barrier-serialized heterogeneous phases, grid tail
// (1024/768), blocks ~75% stalled. Also k0+k3 = ~99us never profiled (top-5
// all k1). Split k1 at the scan boundary:
//   k1a (34.8KB LDS -> 4 blk/CU, full grid resident): in-proj MFMA (z->global)
//       -> conv4+silu -> xp-proj MFMA -> uc/B/C/dt to global. ~86MB writes.
//   k1b (LDS=0, no barriers): scan from global (B/C/dt are lane-broadcast
//       L2/L3-resident reads; uc/z coalesced), 1-deep prefetch, DPP pair-swap,
//       z-mul + dir-layout YF write fused.
// This doubles as the per-phase ablation: rocprof now times each phase.
//
//  K0: fold out_w*fuse_w -> MT16; in_w/xp_w -> bf16; x -> xhwc16 AND xwhc16.
//  K3 (66,560B LDS, 2 blk/CU): contiguous gather, MFMA vs MT16, LN, SiLU.

typedef __attribute__((ext_vector_type(8))) short short8;
typedef __attribute__((ext_vector_type(4))) float f32x4;
typedef __attribute__((ext_vector_type(2))) float f32x2;

__device__ __forceinline__ f32x2 pk_mul(f32x2 a, f32x2 b) {
  f32x2 d;
  asm("v_pk_mul_f32 %0, %1, %2" : "=v"(d) : "v"(a), "v"(b));
  return d;
}
__device__ __forceinline__ f32x2 pk_fma(f32x2 a, f32x2 b, f32x2 c) {
  f32x2 d;
  asm("v_pk_fma_f32 %0, %1, %2, %3" : "=v"(d) : "v"(a), "v"(b), "v"(c));
  return d;
}

__device__ __forceinline__ unsigned int pk2bf(float a, float b) {
  __hip_bfloat162 h = __float22bfloat162_rn(make_float2(a, b));
  unsigned int u;
  __builtin_memcpy(&u, &h, 4);
  return u;
}
__device__ __forceinline__ unsigned short f2bf(float f) {
  __hip_bfloat16 h = __float2bfloat16(f);
  unsigned short s;
  __builtin_memcpy(&s, &h, 2);
  return s;
}
__device__ __forceinline__ float bf2f(unsigned short h) {
  return __uint_as_float(((unsigned int)h) << 16);
}
__device__ __forceinline__ float fastrcp(float x) { return __builtin_amdgcn_rcpf(x); }
__device__ __forceinline__ float siluf(float x) { return x * fastrcp(1.f + __expf(-x)); }

// ---------------------------------------------------------------- K0
// blk 0..127: fold -> MT16. 128..159: in_w -> W16. 160..163: xp_w -> XW16.
// blk 164..419: x[b][c][h][w] -> xhwc16[b][h][w][c] AND xwhc16[b][w][h][c].
__global__ void k0_prep(const float* __restrict__ out_w, const float* __restrict__ fuse_w,
                        const float* __restrict__ in_w, const float* __restrict__ xp_w,
                        const float* __restrict__ x,
                        unsigned short* __restrict__ MT16, unsigned short* __restrict__ W16,
                        unsigned short* __restrict__ XW16, unsigned short* __restrict__ XH,
                        unsigned short* __restrict__ XW) {
  __shared__ unsigned short sT[64*132];   // transpose stage (blk>=164 only)
  int blk = blockIdx.x;
  int tid = threadIdx.x;
  if (blk < 128) {
    int idx = blk * 256 + tid;   // 32768
    int d   = idx & 127;
    int o   = (idx >> 7) & 63;
    int dir = idx >> 13;
    float acc = 0.f;
    #pragma unroll 8
    for (int j = 0; j < 64; ++j)
      acc += out_w[(dir*64 + j)*128 + d] * fuse_w[o*256 + dir*64 + j];
    MT16[o*512 + dir*128 + d] = f2bf(acc);   // M^T layout [o][j=dir*128+d]
  } else if (blk < 160) {
    int t = (blk - 128) * 256 + tid;
    int base = t * 8;                        // 65536 total
    float4 v0 = *(const float4*)(in_w + base);
    float4 v1 = *(const float4*)(in_w + base + 4);
    uint4 pk;
    pk.x = pk2bf(v0.x, v0.y);
    pk.y = pk2bf(v0.z, v0.w);
    pk.z = pk2bf(v1.x, v1.y);
    pk.w = pk2bf(v1.z, v1.w);
    *(uint4*)(W16 + base) = pk;
  } else if (blk < 164) {
    int t = (blk - 160) * 256 + tid;        // 1024 threads
    for (int pid = t; pid < 4*48*128; pid += 1024) {
      int dir = pid / 6144;
      int rem = pid - dir*6144;
      int row = rem >> 7, c = rem & 127;
      XW16[pid] = (row < 36) ? f2bf(xp_w[dir*4608 + row*128 + c]) : (unsigned short)0;
    }
  } else {
    int idx = blk - 164;                    // 0..255
    int b = idx >> 7, h = idx & 127;
    for (int f = tid*4; f < 8192; f += 1024) {
      int c = f >> 7, w = f & 127;
      float4 v = *(const float4*)(x + (((size_t)(b*64 + c)*128 + h)*128 + w));
      sT[c*132 + w + 0] = f2bf(v.x);
      sT[c*132 + w + 1] = f2bf(v.y);
      sT[c*132 + w + 2] = f2bf(v.z);
      sT[c*132 + w + 3] = f2bf(v.w);
    }
    __syncthreads();
    for (int f = tid*8; f < 8192; f += 2048) {
      int w = f >> 6, c0 = f & 63;
      unsigned int pk[4];
      #pragma unroll
      for (int p = 0; p < 4; ++p) {
        unsigned int lo = sT[(c0 + p*2 + 0)*132 + w];
        unsigned int hi = sT[(c0 + p*2 + 1)*132 + w];
        pk[p] = lo | (hi << 16);
      }
      uint4 v; v.x = pk[0]; v.y = pk[1]; v.z = pk[2]; v.w = pk[3];
      *(uint4*)(XH + (((size_t)(b*128 + h)*128 + w)*64 + c0)) = v;
      *(uint4*)(XW + (((size_t)(b*128 + w)*128 + h)*64 + c0)) = v;
    }
  }
}

// ---------------------------------------------------------------- K1a (proj front)
// LDS = sUC only: bf16 [128 tok][136] = 34,816 B -> 4 blocks/CU, grid fully
// resident. Outputs (global):
//   UCg bf16 [n_all][tok][128]           (conv'd+silu'd u)
//   ZFg bf16 [n_all][tok][128]           (silu(z))
//   BCg fp32 [n_all][g 0..8][tok][4]     (g0 = dt-rank, g1..4 = B, g5..8 = C)
__global__ __launch_bounds__(256, 4) void k1a_front(
    const unsigned short* __restrict__ XH, const unsigned short* __restrict__ XW,
    const unsigned short* __restrict__ W16, const unsigned short* __restrict__ XW16,
    const float* __restrict__ conv_w, const float* __restrict__ conv_b,
    unsigned short* __restrict__ UCg, unsigned short* __restrict__ ZFg,
    float* __restrict__ BCg)
{
  __shared__ __align__(16) unsigned short sUC[128*136];   // 34,816 B

  const int tid = threadIdx.x;
  const int dir = blockIdx.x >> 8;
  const int n   = blockIdx.x & 255;
  const int b   = n >> 7;
  const int r   = n & 127;
  const int n_all = dir*256 + n;

  const unsigned short* xsrc = (dir < 2 ? XH : XW) + ((size_t)(b*128 + r)*128)*64;

  const int wave = tid >> 6;
  const int lane = tid & 63;
  const int m16 = lane & 15;
  const int quad = lane >> 4;
  const int tb0 = wave * 32;
  const int st0 = tb0 + m16;
  const int st1 = tb0 + 16 + m16;
  const int sp0 = (dir & 1) ? (127 - st0) : st0;
  const int sp1 = (dir & 1) ? (127 - st1) : st1;

  // ---- phase 2: MFMA in-projection. u rows -> sUC; z rows -> silu -> ZFg. ----
  {
    short8 bfr[2][2];
    #pragma unroll
    for (int ks = 0; ks < 2; ++ks) {
      bfr[0][ks] = *(const short8*)(xsrc + sp0*64 + ks*32 + quad*8);
      bfr[1][ks] = *(const short8*)(xsrc + sp1*64 + ks*32 + quad*8);
    }
    const unsigned short* Wd = W16 + (size_t)dir * 16384;

    // u rows (rt 0..7) -> sUC
    for (int rt = 0; rt < 8; ++rt) {
      short8 af[2];
      #pragma unroll
      for (int ks = 0; ks < 2; ++ks)
        af[ks] = *(const short8*)(Wd + (rt*16 + m16)*64 + ks*32 + quad*8);
      #pragma unroll
      for (int tt = 0; tt < 2; ++tt) {
        f32x4 acc = {0.f, 0.f, 0.f, 0.f};
        acc = __builtin_amdgcn_mfma_f32_16x16x32_bf16(af[0], bfr[tt][0], acc, 0, 0, 0);
        acc = __builtin_amdgcn_mfma_f32_16x16x32_bf16(af[1], bfr[tt][1], acc, 0, 0, 0);
        const int tok = tt ? st1 : st0;
        const int r0 = rt*16 + quad*4;
        uint2 u2;
        u2.x = pk2bf(acc[0], acc[1]);
        u2.y = pk2bf(acc[2], acc[3]);
        *(uint2*)(sUC + tok*136 + r0) = u2;
      }
    }
    // z rows (rt 8..15) -> silu -> ZFg global
    unsigned short* zn = ZFg + (size_t)n_all * 16384;
    #pragma unroll
    for (int k = 0; k < 8; ++k) {
      short8 af[2];
      #pragma unroll
      for (int ks = 0; ks < 2; ++ks)
        af[ks] = *(const short8*)(Wd + ((8+k)*16 + m16)*64 + ks*32 + quad*8);
      #pragma unroll
      for (int tt = 0; tt < 2; ++tt) {
        f32x4 acc = {0.f, 0.f, 0.f, 0.f};
        acc = __builtin_amdgcn_mfma_f32_16x16x32_bf16(af[0], bfr[tt][0], acc, 0, 0, 0);
        acc = __builtin_amdgcn_mfma_f32_16x16x32_bf16(af[1], bfr[tt][1], acc, 0, 0, 0);
        const int tok = tt ? st1 : st0;
        uint2 zv;
        zv.x = pk2bf(siluf(acc[0]), siluf(acc[1]));
        zv.y = pk2bf(siluf(acc[2]), siluf(acc[3]));
        *(uint2*)(zn + tok*128 + 16*k + quad*4) = zv;
      }
    }
  }
  __syncthreads();

  // ---- phase 3: causal conv-4 + silu in sUC (bf16), packed 2-chunk. ----
  {
    const int d = tid & 127;
    const int half = tid >> 7;
    const int ca = half * 32;
    const int cb2 = (half + 2) * 32;
    const float* cw = conv_w + (size_t)(dir*128 + d)*4;
    const float c0w = cw[0], c1w = cw[1], c2w = cw[2], c3w = cw[3];
    const float cbv = conv_b[dir*128 + d];
    const f32x2 cw0v = {c0w, c0w}, cw1v = {c1w, c1w}, cw2v = {c2w, c2w}, cw3v = {c3w, c3w};
    const f32x2 cbv2 = {cbv, cbv};
    f32x2 A0 = { half ? bf2f(sUC[(ca-3)*136 + d]) : 0.f, bf2f(sUC[(cb2-3)*136 + d]) };
    f32x2 A1 = { half ? bf2f(sUC[(ca-2)*136 + d]) : 0.f, bf2f(sUC[(cb2-2)*136 + d]) };
    f32x2 A2 = { half ? bf2f(sUC[(ca-1)*136 + d]) : 0.f, bf2f(sUC[(cb2-1)*136 + d]) };
    __syncthreads();
    unsigned short* pa = sUC + ca*136 + d;
    unsigned short* pb = sUC + cb2*136 + d;
    for (int i = 0; i < 32; ++i) {
      f32x2 cur = { bf2f(*pa), bf2f(*pb) };
      f32x2 v = pk_fma(cw3v, cur,
                pk_fma(cw2v, A2,
                pk_fma(cw1v, A1,
                pk_fma(cw0v, A0, cbv2))));
      *pa = f2bf(siluf(v.x));
      *pb = f2bf(siluf(v.y));
      A0 = A1; A1 = A2; A2 = cur;
      pa += 136; pb += 136;
    }
  }
  __syncthreads();

  // ---- phase 4: uc -> UCg copy + MFMA xp-projection -> BCg. ----
  {
    // uc store (coalesced, 2048 uint4 chunks)
    unsigned short* ucn = UCg + (size_t)n_all * 16384;
    #pragma unroll
    for (int c = 0; c < 8; ++c) {
      int idx = tid + c*256;
      int tok = idx >> 4, u4 = idx & 15;
      *(uint4*)(ucn + tok*128 + u4*8) = *(const uint4*)(sUC + tok*136 + u4*8);
    }

    short8 bfr[2][4];
    #pragma unroll
    for (int tt = 0; tt < 2; ++tt)
      #pragma unroll
      for (int ks = 0; ks < 4; ++ks)
        bfr[tt][ks] = *(const short8*)(sUC + (tt ? st1 : st0)*136 + ks*32 + quad*8);

    const unsigned short* XWd = XW16 + (size_t)dir * (48*128);
    float* bcn = BCg + (size_t)n_all * 4608;

    for (int rt = 0; rt < 3; ++rt) {
      short8 af[4];
      #pragma unroll
      for (int ks = 0; ks < 4; ++ks)
        af[ks] = *(const short8*)(XWd + (rt*16 + m16)*128 + ks*32 + quad*8);
      #pragma unroll
      for (int tt = 0; tt < 2; ++tt) {
        f32x4 acc = {0.f, 0.f, 0.f, 0.f};
        #pragma unroll
        for (int ks = 0; ks < 4; ++ks)
          acc = __builtin_amdgcn_mfma_f32_16x16x32_bf16(af[ks], bfr[tt][ks], acc, 0, 0, 0);
        const int tok = tt ? st1 : st0;
        const int g = rt*4 + quad;       // xp-row group: 0=dt, 1..4=B, 5..8=C
        if (g < 9) {
          float4 v; v.x = acc[0]; v.y = acc[1]; v.z = acc[2]; v.w = acc[3];
          *(float4*)(bcn + g*512 + tok*4) = v;
        }
      }
    }
  }
}

// ---------------------------------------------------------------- K1b (scan)
// LDS = 0, no barriers. One block per sequence; thread (d = tid>>1, p = tid&1)
// owns 8 states of channel d. B/C/dt reads are lane-pair-broadcast (L2/L3);
// uc/z coalesced. 1-deep prefetch; DPP quad-perm pair reduce; z-mul + dir-
// dependent YF write fused.
__global__ __launch_bounds__(256, 4) void k1b_scan(
    const unsigned short* __restrict__ UCg, const unsigned short* __restrict__ ZFg,
    const float* __restrict__ BCg,
    const float* __restrict__ dtp_w, const float* __restrict__ dtp_b,
    const float* __restrict__ A_log, const float* __restrict__ Dp,
    unsigned short* __restrict__ YF)
{
  const int tid = threadIdx.x;
  const int dir = blockIdx.x >> 8;
  const int n   = blockIdx.x & 255;
  const int b   = n >> 7;
  const int r   = n & 127;
  const int n_all = dir*256 + n;
  const int d = tid >> 1;
  const int p = tid & 1;

  const float* dwp = dtp_w + (size_t)(dir*128 + d) * 4;
  const float dw0 = dwp[0], dw1 = dwp[1], dw2 = dwp[2], dw3 = dwp[3];
  const float db = dtp_b[dir*128 + d];
  const float dpv = Dp[dir*128 + d];

  float Av[8];
  bool fast = true;
  #pragma unroll
  for (int j = 0; j < 8; ++j) {
    float a = -__expf(A_log[((size_t)(dir*128 + d))*16 + p*8 + j]);
    Av[j] = a;
    if (fabsf((-a) - (float)(p*8 + j + 1)) > 1e-3f) fast = false;
  }

  const float* bcn = BCg + (size_t)n_all * 4608;
  const float* qp  = bcn;                    // g=0 dt, +4 floats/token
  const float* bp0 = bcn + (1 + 2*p)*512;
  const float* bp1 = bcn + (2 + 2*p)*512;
  const float* cp0 = bcn + (5 + 2*p)*512;
  const float* cp1 = bcn + (6 + 2*p)*512;
  const unsigned short* up = UCg + (size_t)n_all*16384 + d;
  const unsigned short* zp = ZFg + (size_t)n_all*16384 + d;

  unsigned short* yo;
  long ystep;
  if (dir < 2) {
    yo = YF + ((size_t)n_all*128)*128 + d;                       ystep = 128;
  } else if (dir == 2) {
    yo = YF + ((size_t)((512 + b*128)*128 + r))*128 + d;         ystep = 16384;
  } else {
    yo = YF + ((size_t)((768 + b*128 + 127)*128 + r))*128 + d;   ystep = -16384;
  }

  if (fast) {
    f32x2 h0 = {0.f,0.f}, h1 = {0.f,0.f}, h2v = {0.f,0.f}, h3 = {0.f,0.f};
    float4 Q   = *(const float4*)(qp);
    float4 Bq0 = *(const float4*)(bp0), Bq1 = *(const float4*)(bp1);
    float4 Cq0 = *(const float4*)(cp0), Cq1 = *(const float4*)(cp1);
    float u  = bf2f(*up);
    float zf = bf2f(*zp);
    for (int l = 0; l < 128; ++l) {
      // prefetch token l+1 (clamped; last prefetch is dead but in-bounds)
      const int a4   = (l < 127) ? 4 : 0;
      const int a128 = (l < 127) ? 128 : 0;
      float4 Qn  = *(const float4*)(qp  + a4);
      float4 Bn0 = *(const float4*)(bp0 + a4);
      float4 Bn1 = *(const float4*)(bp1 + a4);
      float4 Cn0 = *(const float4*)(cp0 + a4);
      float4 Cn1 = *(const float4*)(cp1 + a4);
      float un   = bf2f(up[a128]);
      float zn   = bf2f(zp[a128]);

      float dr = Q.x*dw0 + Q.y*dw1 + Q.z*dw2 + Q.w*dw3 + db;
      float te = __expf(dr);
      float dt = (dr > 20.f) ? dr : __logf(1.f + te);
      float dtu = dt * u;
      float E = fastrcp(1.f + te);
      float E2 = E*E, E4 = E2*E2, E8 = E4*E4;
      float eb = p ? E8 : 1.f;
      f32x2 P0 = {E*eb, E2*eb};
      f32x2 E2v = {E2, E2};
      f32x2 P1 = pk_mul(P0, E2v);
      f32x2 P2 = pk_mul(P1, E2v);
      f32x2 P3 = pk_mul(P2, E2v);
      f32x2 du = {dtu, dtu};
      f32x2 B01 = {Bq0.x,Bq0.y}, B23 = {Bq0.z,Bq0.w};
      f32x2 B45 = {Bq1.x,Bq1.y}, B67 = {Bq1.z,Bq1.w};
      f32x2 C01 = {Cq0.x,Cq0.y}, C23 = {Cq0.z,Cq0.w};
      f32x2 C45 = {Cq1.x,Cq1.y}, C67 = {Cq1.z,Cq1.w};
      h0  = pk_fma(h0,  P0, pk_mul(du, B01));
      h1  = pk_fma(h1,  P1, pk_mul(du, B23));
      h2v = pk_fma(h2v, P2, pk_mul(du, B45));
      h3  = pk_fma(h3,  P3, pk_mul(du, B67));
      f32x2 ya = pk_mul(h0, C01);
      f32x2 yb = pk_mul(h1, C23);
      ya = pk_fma(h2v, C45, ya);
      yb = pk_fma(h3,  C67, yb);
      float ypar = (ya.x + ya.y) + (yb.x + yb.y);
      float ot = __uint_as_float((unsigned int)__builtin_amdgcn_mov_dpp(
                   (int)__float_as_uint(ypar), 0xB1, 0xF, 0xF, true));
      float ysum = ypar + ot;                  // identical on both pair lanes
      *yo = f2bf((ysum + u*dpv) * zf);         // both lanes same value/addr: benign
      yo += ystep;
      qp += 4; bp0 += 4; bp1 += 4; cp0 += 4; cp1 += 4; up += 128; zp += 128;
      Q = Qn; Bq0 = Bn0; Bq1 = Bn1; Cq0 = Cn0; Cq1 = Cn1; u = un; zf = zn;
    }
  } else {
    float h[8];
    #pragma unroll
    for (int j = 0; j < 8; ++j) h[j] = 0.f;
    for (int l = 0; l < 128; ++l) {
      float4 Q   = *(const float4*)(qp);
      float4 Bq0 = *(const float4*)(bp0), Bq1 = *(const float4*)(bp1);
      float4 Cq0 = *(const float4*)(cp0), Cq1 = *(const float4*)(cp1);
      float Bv[8] = {Bq0.x,Bq0.y,Bq0.z,Bq0.w, Bq1.x,Bq1.y,Bq1.z,Bq1.w};
      float Cv[8] = {Cq0.x,Cq0.y,Cq0.z,Cq0.w, Cq1.x,Cq1.y,Cq1.z,Cq1.w};
      float u  = bf2f(*up);
      float zf = bf2f(*zp);
      float dr = Q.x*dw0 + Q.y*dw1 + Q.z*dw2 + Q.w*dw3 + db;
      float te = __expf(dr);
      float dt = (dr > 20.f) ? dr : __logf(1.f + te);
      float dtu = dt * u;
      float yp = 0.f;
      #pragma unroll
      for (int j = 0; j < 8; ++j) {
        float ej = __expf(dt*Av[j]);
        h[j] = h[j]*ej + dtu*Bv[j];
        yp += h[j]*Cv[j];
      }
      float ot = __uint_as_float((unsigned int)__builtin_amdgcn_mov_dpp(
                   (int)__float_as_uint(yp), 0xB1, 0xF, 0xF, true));
      float ysum = yp + ot;
      *yo = f2bf((ysum + u*dpv) * zf);
      yo += ystep;
      qp += 4; bp0 += 4; bp1 += 4; cp0 += 4; cp1 += 4; up += 128; zp += 128;
    }
  }
}

// ---------------------------------------------------------------- K3 (MFMA fuse + LN)
__global__ __launch_bounds__(256, 2) void k3_fuse(
    const unsigned short* __restrict__ YF, const unsigned short* __restrict__ MT16,
    const float* __restrict__ fuse_b, const float* __restrict__ ln_g,
    const float* __restrict__ ln_b, float* __restrict__ out)
{
  __shared__ __align__(16) unsigned short sYB[64*520];   // 66,560 B

  const int tid = threadIdx.x;
  const int blk = blockIdx.x;             // 512
  const int b = blk >> 8;
  const int rr2 = blk & 255;
  const int h = rr2 >> 1;
  const int w0 = (rr2 & 1) * 64;

  for (int f = tid*8; f < 32768; f += 2048) {
    int dirg = f >> 13;
    int rem = f & 8191;
    int tok = rem >> 7;
    int dd = rem & 127;
    int X = (dirg == 1) ? (127 - w0 - tok) : (w0 + tok);
    size_t base = ((size_t)(dirg*256 + b*128 + h)*128 + X)*128 + dd;
    *(uint4*)(sYB + tok*520 + dirg*128 + dd) = *(const uint4*)(YF + base);
  }
  __syncthreads();

  const int wave = tid >> 6;
  const int lane = tid & 63;
  const int m16 = lane & 15;
  const int quad = lane >> 4;
  const int tok = wave*16 + m16;

  short8 bfr[16];
  #pragma unroll
  for (int jt = 0; jt < 16; ++jt)
    bfr[jt] = *(const short8*)(sYB + tok*520 + jt*32 + quad*8);

  float facc[4][4];
  #pragma unroll
  for (int mt = 0; mt < 4; ++mt) {
    f32x4 acc = {0.f, 0.f, 0.f, 0.f};
    #pragma unroll
    for (int jt = 0; jt < 16; ++jt) {
      short8 af = *(const short8*)(MT16 + (size_t)(mt*16 + m16)*512 + jt*32 + quad*8);
      acc = __builtin_amdgcn_mfma_f32_16x16x32_bf16(af, bfr[jt], acc, 0, 0, 0);
    }
    facc[mt][0] = acc[0]; facc[mt][1] = acc[1]; facc[mt][2] = acc[2]; facc[mt][3] = acc[3];
  }

  float fv[16];
  float s1 = 0.f, s2 = 0.f;
  #pragma unroll
  for (int mt = 0; mt < 4; ++mt)
    #pragma unroll
    for (int rr = 0; rr < 4; ++rr) {
      int o = mt*16 + quad*4 + rr;
      float v = facc[mt][rr] + fuse_b[o];
      fv[mt*4 + rr] = v;
      s1 += v; s2 += v*v;
    }
  s1 += __shfl_xor(s1, 16, 64); s1 += __shfl_xor(s1, 32, 64);
  s2 += __shfl_xor(s2, 16, 64); s2 += __shfl_xor(s2, 32, 64);
  float mu = s1 * (1.f/64.f);
  float var = s2 * (1.f/64.f) - mu*mu;
  float rs = rsqrtf(var + 1e-5f);

  #pragma unroll
  for (int mt = 0; mt < 4; ++mt)
    #pragma unroll
    for (int rr = 0; rr < 4; ++rr) {
      int o = mt*16 + quad*4 + rr;
      float v = (fv[mt*4 + rr] - mu) * rs * ln_g[o] + ln_b[o];
      out[((size_t)(b*64 + o)*128 + h)*128 + (w0 + tok)] = siluf(v);
    }
}

// ---------------------------------------------------------------- host
extern "C" void kernel_launch(void* const* d_in, const int* in_sizes, int n_in,
                              void* d_out, int out_size, void* d_ws, size_t ws_size,
                              hipStream_t stream) {
  const float* x      = (const float*)d_in[0];
  const float* in_w   = (const float*)d_in[1];
  const float* conv_w = (const float*)d_in[2];
  const float* conv_b = (const float*)d_in[3];
  const float* xp_w   = (const float*)d_in[4];
  const float* dtp_w  = (const float*)d_in[5];
  const float* dtp_b  = (const float*)d_in[6];
  const float* A_log  = (const float*)d_in[7];
  const float* Dp     = (const float*)d_in[8];
  const float* out_w  = (const float*)d_in[9];
  const float* fuse_w = (const float*)d_in[10];
  const float* fuse_b = (const float*)d_in[11];
  const float* ln_g   = (const float*)d_in[12];
  const float* ln_b   = (const float*)d_in[13];
  float* out = (float*)d_out;

  // ws layout (BYTES):
  char* ws = (char*)d_ws;
  unsigned short* YF   = (unsigned short*)(ws);              // 33,554,432 (yf, dir-layouts)
  unsigned short* MT16 = (unsigned short*)(ws + 33554432);   //     65,536
  unsigned short* W16  = (unsigned short*)(ws + 33619968);   //    131,072
  unsigned short* XW16 = (unsigned short*)(ws + 33751040);   //     49,152
  unsigned short* XH   = (unsigned short*)(ws + 33800192);   //  4,194,304 (xhwc16)
  unsigned short* XWt  = (unsigned short*)(ws + 37994496);   //  4,194,304 (xwhc16)
  unsigned short* UCg  = (unsigned short*)(ws + 42188800);   // 33,554,432 (uc bf16)
  unsigned short* ZFg  = (unsigned short*)(ws + 75743232);   // 33,554,432 (silu(z) bf16)
  float*          BCg  = (float*)(ws + 109297664);           // 18,874,368 (dt/B/C fp32)
  // total 128,172,032 B

  k0_prep<<<dim3(420), dim3(256), 0, stream>>>(out_w, fuse_w, in_w, xp_w, x,
                                               MT16, W16, XW16, XH, XWt);
  k1a_front<<<dim3(1024), dim3(256), 0, stream>>>(XH, XWt, W16, XW16, conv_w, conv_b,
                                                  UCg, ZFg, BCg);
  k1b_scan<<<dim3(1024), dim3(256), 0, stream>>>(UCg, ZFg, BCg, dtp_w, dtp_b,
                                                 A_log, Dp, YF);
  k3_fuse<<<dim3(512), dim3(256), 0, stream>>>(YF, MT16, fuse_b, ln_g, ln_b, out);
}

// Round 4
// 248.321 us; speedup vs baseline: 1.0984x; 1.0984x over previous
//
#include <hip/hip_runtime.h>
#include <hip/hip_bf16.h>
#include <math.h>

// MambaBlock: 4-direction 2D selective scan + fuse + LN + SiLU
// B=2, H=W=128, D_MODEL=64, D_INNER=128, D_STATE=16, DT_RANK=4, D_CONV=4
//
// R15 = fused k1 at 512 threads / 2 blocks/CU. R14's fission showed: scan
// operands MUST stay in LDS (global-scan = 140us, 2600 cy/token); front
// phases ~34us; and the real fused-k1 problem is scheduling-round waste:
// 1024 blocks @ 3/CU = 768 slots -> 1.33 rounds, avg ~8 waves/CU. Now:
// 512-thr blocks, 2/CU (LDS padded to 55,296B to forbid a 3rd), 1024/512
// = exactly 2 rounds, 16 waves/CU throughout. Phases: 2/4 -> 8 waves x 16
// tokens; conv -> 4-way chunk parallel; scan -> 4 thr/channel (4 states,
// quad DPP reduce). Operand layout in LDS unchanged from R11.
//
//  K0: fold out_w*fuse_w -> MT16; in_w/xp_w -> bf16; x -> xhwc16 AND xwhc16.
//  K3 (66,560B LDS, 2 blk/CU): contiguous gather, MFMA vs MT16, LN, SiLU.

typedef __attribute__((ext_vector_type(8))) short short8;
typedef __attribute__((ext_vector_type(4))) float f32x4;
typedef __attribute__((ext_vector_type(2))) float f32x2;

__device__ __forceinline__ f32x2 pk_mul(f32x2 a, f32x2 b) {
  f32x2 d;
  asm("v_pk_mul_f32 %0, %1, %2" : "=v"(d) : "v"(a), "v"(b));
  return d;
}
__device__ __forceinline__ f32x2 pk_fma(f32x2 a, f32x2 b, f32x2 c) {
  f32x2 d;
  asm("v_pk_fma_f32 %0, %1, %2, %3" : "=v"(d) : "v"(a), "v"(b), "v"(c));
  return d;
}

__device__ __forceinline__ unsigned int pk2bf(float a, float b) {
  __hip_bfloat162 h = __float22bfloat162_rn(make_float2(a, b));
  unsigned int u;
  __builtin_memcpy(&u, &h, 4);
  return u;
}
__device__ __forceinline__ unsigned short f2bf(float f) {
  __hip_bfloat16 h = __float2bfloat16(f);
  unsigned short s;
  __builtin_memcpy(&s, &h, 2);
  return s;
}
__device__ __forceinline__ float bf2f(unsigned short h) {
  return __uint_as_float(((unsigned int)h) << 16);
}
__device__ __forceinline__ float fastrcp(float x) { return __builtin_amdgcn_rcpf(x); }
__device__ __forceinline__ float siluf(float x) { return x * fastrcp(1.f + __expf(-x)); }

// ---------------------------------------------------------------- K0
// blk 0..127: fold -> MT16. 128..159: in_w -> W16. 160..163: xp_w -> XW16.
// blk 164..419: x[b][c][h][w] -> xhwc16[b][h][w][c] AND xwhc16[b][w][h][c].
__global__ void k0_prep(const float* __restrict__ out_w, const float* __restrict__ fuse_w,
                        const float* __restrict__ in_w, const float* __restrict__ xp_w,
                        const float* __restrict__ x,
                        unsigned short* __restrict__ MT16, unsigned short* __restrict__ W16,
                        unsigned short* __restrict__ XW16, unsigned short* __restrict__ XH,
                        unsigned short* __restrict__ XW) {
  __shared__ unsigned short sT[64*132];   // transpose stage (blk>=164 only)
  int blk = blockIdx.x;
  int tid = threadIdx.x;
  if (blk < 128) {
    int idx = blk * 256 + tid;   // 32768
    int d   = idx & 127;
    int o   = (idx >> 7) & 63;
    int dir = idx >> 13;
    float acc = 0.f;
    #pragma unroll 8
    for (int j = 0; j < 64; ++j)
      acc += out_w[(dir*64 + j)*128 + d] * fuse_w[o*256 + dir*64 + j];
    MT16[o*512 + dir*128 + d] = f2bf(acc);   // M^T layout [o][j=dir*128+d]
  } else if (blk < 160) {
    int t = (blk - 128) * 256 + tid;
    int base = t * 8;                        // 65536 total
    float4 v0 = *(const float4*)(in_w + base);
    float4 v1 = *(const float4*)(in_w + base + 4);
    uint4 pk;
    pk.x = pk2bf(v0.x, v0.y);
    pk.y = pk2bf(v0.z, v0.w);
    pk.z = pk2bf(v1.x, v1.y);
    pk.w = pk2bf(v1.z, v1.w);
    *(uint4*)(W16 + base) = pk;
  } else if (blk < 164) {
    int t = (blk - 160) * 256 + tid;        // 1024 threads
    for (int pid = t; pid < 4*48*128; pid += 1024) {
      int dir = pid / 6144;
      int rem = pid - dir*6144;
      int row = rem >> 7, c = rem & 127;
      XW16[pid] = (row < 36) ? f2bf(xp_w[dir*4608 + row*128 + c]) : (unsigned short)0;
    }
  } else {
    int idx = blk - 164;                    // 0..255
    int b = idx >> 7, h = idx & 127;
    for (int f = tid*4; f < 8192; f += 1024) {
      int c = f >> 7, w = f & 127;
      float4 v = *(const float4*)(x + (((size_t)(b*64 + c)*128 + h)*128 + w));
      sT[c*132 + w + 0] = f2bf(v.x);
      sT[c*132 + w + 1] = f2bf(v.y);
      sT[c*132 + w + 2] = f2bf(v.z);
      sT[c*132 + w + 3] = f2bf(v.w);
    }
    __syncthreads();
    for (int f = tid*8; f < 8192; f += 2048) {
      int w = f >> 6, c0 = f & 63;
      unsigned int pk[4];
      #pragma unroll
      for (int p = 0; p < 4; ++p) {
        unsigned int lo = sT[(c0 + p*2 + 0)*132 + w];
        unsigned int hi = sT[(c0 + p*2 + 1)*132 + w];
        pk[p] = lo | (hi << 16);
      }
      uint4 v; v.x = pk[0]; v.y = pk[1]; v.z = pk[2]; v.w = pk[3];
      *(uint4*)(XH + (((size_t)(b*128 + h)*128 + w)*64 + c0)) = v;
      *(uint4*)(XW + (((size_t)(b*128 + w)*128 + h)*64 + c0)) = v;
    }
  }
}

// ---------------------------------------------------------------- K1 (fused, 512 thr)
// LDS (55,296 B declared; 53,248 used -> padded so only 2 blocks/CU fit,
// keeping 1024 blocks = exactly 2 full scheduling rounds, 16 waves/CU):
//   sBCf @0     18432B fp32 [128 tok][36] (B cols 0..15, C cols 16..31) [ph4+]
//   sUC  @18432 34816B bf16 [128 tok][136]; cols 0..127 = u_pre -> uc -> y;
//                      cols 128..135 = dt-rank float4 [ph4+]
__global__ __launch_bounds__(512, 2) void k1_front(
    const unsigned short* __restrict__ XH, const unsigned short* __restrict__ XW,
    const unsigned short* __restrict__ W16, const unsigned short* __restrict__ XW16,
    const float* __restrict__ conv_w, const float* __restrict__ conv_b,
    const float* __restrict__ dtp_w, const float* __restrict__ dtp_b,
    const float* __restrict__ A_log, const float* __restrict__ Dp,
    unsigned short* __restrict__ YF)
{
  __shared__ __align__(16) char smem[55296];
  float* sBCf         = (float*)smem;                      // [128][36]  (ph4+)
  unsigned short* sUC = (unsigned short*)(smem + 18432);   // [128][136]

  const int tid = threadIdx.x;
  const int dir = blockIdx.x >> 8;
  const int n   = blockIdx.x & 255;
  const int b   = n >> 7;
  const int r   = n & 127;
  const int n_all = dir*256 + n;

  const unsigned short* xsrc = (dir < 2 ? XH : XW) + ((size_t)(b*128 + r)*128)*64;

  const int wave = tid >> 6;          // 0..7: owns token group wave*16
  const int lane = tid & 63;
  const int m16 = lane & 15;
  const int quad = lane >> 4;
  const int st = wave*16 + m16;       // scan-order token owned in MFMA phases
  const int sp = (dir & 1) ? (127 - st) : st;   // spatial index in xsrc

  unsigned int zpk[8][2];   // silu(z) bf16-packed for token st: [k][pair] (16 VGPRs)

  // ---- phase 2: MFMA in-projection. A=in_w (global bf16), B=x (global bf16).
  //      Each wave: its 16 tokens, all 16 row-tiles (8 u -> sUC, 8 z -> regs).
  {
    short8 bfr[2];
    #pragma unroll
    for (int ks = 0; ks < 2; ++ks)
      bfr[ks] = *(const short8*)(xsrc + sp*64 + ks*32 + quad*8);
    const unsigned short* Wd = W16 + (size_t)dir * 16384;

    // u rows (rt 0..7)
    for (int rt = 0; rt < 8; ++rt) {
      short8 af[2];
      #pragma unroll
      for (int ks = 0; ks < 2; ++ks)
        af[ks] = *(const short8*)(Wd + (rt*16 + m16)*64 + ks*32 + quad*8);
      f32x4 acc = {0.f, 0.f, 0.f, 0.f};
      acc = __builtin_amdgcn_mfma_f32_16x16x32_bf16(af[0], bfr[0], acc, 0, 0, 0);
      acc = __builtin_amdgcn_mfma_f32_16x16x32_bf16(af[1], bfr[1], acc, 0, 0, 0);
      const int r0 = rt*16 + quad*4;
      uint2 u2;
      u2.x = pk2bf(acc[0], acc[1]);
      u2.y = pk2bf(acc[2], acc[3]);
      *(uint2*)(sUC + st*136 + r0) = u2;
    }
    // z rows (rt 8..15) -> registers
    #pragma unroll
    for (int k = 0; k < 8; ++k) {
      short8 af[2];
      #pragma unroll
      for (int ks = 0; ks < 2; ++ks)
        af[ks] = *(const short8*)(Wd + ((8+k)*16 + m16)*64 + ks*32 + quad*8);
      f32x4 acc = {0.f, 0.f, 0.f, 0.f};
      acc = __builtin_amdgcn_mfma_f32_16x16x32_bf16(af[0], bfr[0], acc, 0, 0, 0);
      acc = __builtin_amdgcn_mfma_f32_16x16x32_bf16(af[1], bfr[1], acc, 0, 0, 0);
      zpk[k][0] = pk2bf(siluf(acc[0]), siluf(acc[1]));
      zpk[k][1] = pk2bf(siluf(acc[2]), siluf(acc[3]));
    }
  }
  __syncthreads();

  // ---- phase 3: causal conv-4 + silu in sUC (bf16). 4 chunks of 32 tokens,
  //      fully parallel: thread (d = tid&127, chunk = tid>>7).
  {
    const int d = tid & 127;
    const int c = tid >> 7;            // chunk 0..3
    const int ca = c * 32;
    const float* cw = conv_w + (size_t)(dir*128 + d)*4;
    const float c0w = cw[0], c1w = cw[1], c2w = cw[2], c3w = cw[3];
    const float cbv = conv_b[dir*128 + d];
    float a0 = c ? bf2f(sUC[(ca-3)*136 + d]) : 0.f;
    float a1 = c ? bf2f(sUC[(ca-2)*136 + d]) : 0.f;
    float a2 = c ? bf2f(sUC[(ca-1)*136 + d]) : 0.f;
    __syncthreads();                   // all predecessor reads before any write
    unsigned short* pa = sUC + ca*136 + d;
    for (int i = 0; i < 32; ++i) {
      float cur = bf2f(*pa);
      float v = cbv + c0w*a0 + c1w*a1 + c2w*a2 + c3w*cur;
      *pa = f2bf(siluf(v));
      a0 = a1; a1 = a2; a2 = cur;
      pa += 136;
    }
  }
  __syncthreads();

  // ---- phase 4: MFMA xp-projection. A=xp_w (global bf16), B=uc (LDS sUC).
  //      Each wave: its 16 tokens, rt 0..2. dt rows -> sUC cols 128..135;
  //      B/C rows -> sBCf (fp32).
  {
    short8 bfr[4];
    #pragma unroll
    for (int ks = 0; ks < 4; ++ks)
      bfr[ks] = *(const short8*)(sUC + st*136 + ks*32 + quad*8);

    const unsigned short* XWd = XW16 + (size_t)dir * (48*128);

    for (int rt = 0; rt < 3; ++rt) {
      short8 af[4];
      #pragma unroll
      for (int ks = 0; ks < 4; ++ks)
        af[ks] = *(const short8*)(XWd + (rt*16 + m16)*128 + ks*32 + quad*8);
      f32x4 acc = {0.f, 0.f, 0.f, 0.f};
      #pragma unroll
      for (int ks = 0; ks < 4; ++ks)
        acc = __builtin_amdgcn_mfma_f32_16x16x32_bf16(af[ks], bfr[ks], acc, 0, 0, 0);
      const int r0 = rt*16 + quad*4;   // 0,4,...,44
      if (r0 == 0) {
        float4 v; v.x = acc[0]; v.y = acc[1]; v.z = acc[2]; v.w = acc[3];
        *(float4*)(smem + 18432 + st*272 + 256) = v;      // sUC cols 128..135
      } else if (r0 < 36) {
        float4 v; v.x = acc[0]; v.y = acc[1]; v.z = acc[2]; v.w = acc[3];
        *(float4*)(sBCf + st*36 + (r0 - 4)) = v;          // B: 0..15, C: 16..31
      }
    }
  }
  __syncthreads();

  // ---- phase 5: selective scan, 4 threads/channel (4 states each). ----
  //      d = tid>>2, p = tid&3 (quad lanes). Quad DPP reduce (2 ops), all
  //      lanes get the bit-identical sum (FP add commutativity).
  {
    const int d = tid >> 2;
    const int p = tid & 3;
    const float* dwp = dtp_w + (size_t)(dir*128 + d) * 4;
    const float dw0 = dwp[0], dw1 = dwp[1], dw2 = dwp[2], dw3 = dwp[3];
    const float db = dtp_b[dir*128 + d];
    const float dpv = Dp[dir*128 + d];

    float Av[4];
    bool fast = true;
    #pragma unroll
    for (int j = 0; j < 4; ++j) {
      float a = -__expf(A_log[((size_t)(dir*128 + d))*16 + p*4 + j]);
      Av[j] = a;
      if (fabsf((-a) - (float)(p*4 + j + 1)) > 1e-3f) fast = false;
    }

    if (fast) {
      // E = exp(-softplus(dr)) = 1/(1+exp(dr)); state j uses E^(4p+j+1).
      f32x2 h0 = {0.f, 0.f}, h1 = {0.f, 0.f};
      const char* qp = smem + 18432 + 256;             // dt float4, +272/tok
      const float* bp = sBCf + p*4;                    // B quad, +36/tok
      const float* cp = sBCf + 16 + p*4;               // C quad, +36/tok
      const unsigned short* up = sUC + d;              // u,  +136/tok
      unsigned short* yo = sUC + d;                    // y,  +136/tok
      for (int l = 0; l < 128; ++l) {
        float4 Q  = *(const float4*)qp;
        float4 Bq = *(const float4*)bp;
        float4 Cq = *(const float4*)cp;
        float u = bf2f(*up);
        float dr = Q.x*dw0 + Q.y*dw1 + Q.z*dw2 + Q.w*dw3 + db;
        float te = __expf(dr);
        float dt = (dr > 20.f) ? dr : __logf(1.f + te);
        float dtu = dt * u;
        float E = fastrcp(1.f + te);
        float E2 = E*E, E4 = E2*E2, E8 = E4*E4;
        float m1 = (p & 1) ? E4 : 1.f;
        float m2 = (p & 2) ? E8 : 1.f;
        float eb = m1 * m2;                         // E^(4p)
        f32x2 Ee = {E, E2};
        f32x2 ebv = {eb, eb};
        f32x2 P0 = pk_mul(Ee, ebv);                 // {E^(4p+1), E^(4p+2)}
        f32x2 E2v = {E2, E2};
        f32x2 P1 = pk_mul(P0, E2v);                 // {E^(4p+3), E^(4p+4)}
        f32x2 du = {dtu, dtu};
        f32x2 B01 = {Bq.x, Bq.y}, B23 = {Bq.z, Bq.w};
        f32x2 C01 = {Cq.x, Cq.y}, C23 = {Cq.z, Cq.w};
        h0 = pk_fma(h0, P0, pk_mul(du, B01));
        h1 = pk_fma(h1, P1, pk_mul(du, B23));
        f32x2 ya = pk_mul(h0, C01);
        ya = pk_fma(h1, C23, ya);
        float ypar = ya.x + ya.y;
        // quad reduce: lanes p0..p3 -> same sum on all 4 (commutative adds)
        float t1 = __uint_as_float((unsigned int)__builtin_amdgcn_mov_dpp(
                     (int)__float_as_uint(ypar), 0xB1, 0xF, 0xF, true)); // [1,0,3,2]
        float s1 = ypar + t1;
        float t2 = __uint_as_float((unsigned int)__builtin_amdgcn_mov_dpp(
                     (int)__float_as_uint(s1), 0x4E, 0xF, 0xF, true));   // [2,3,0,1]
        float ysum = s1 + t2;
        *yo = f2bf(ysum + u*dpv);        // all 4 lanes: same value, same addr
        qp += 272; bp += 36; cp += 36; up += 136; yo += 136;
      }
    } else {
      float h[4];
      #pragma unroll
      for (int j = 0; j < 4; ++j) h[j] = 0.f;
      for (int l = 0; l < 128; ++l) {
        float4 Q  = *(const float4*)(smem + 18432 + l*272 + 256);
        float4 Bq = *(const float4*)(sBCf + l*36 + p*4);
        float4 Cq = *(const float4*)(sBCf + l*36 + 16 + p*4);
        float Bv[4] = {Bq.x, Bq.y, Bq.z, Bq.w};
        float Cv[4] = {Cq.x, Cq.y, Cq.z, Cq.w};
        float u = bf2f(sUC[l*136 + d]);
        float dr = Q.x*dw0 + Q.y*dw1 + Q.z*dw2 + Q.w*dw3 + db;
        float te = __expf(dr);
        float dt = (dr > 20.f) ? dr : __logf(1.f + te);
        float dtu = dt * u;
        float yp = 0.f;
        #pragma unroll
        for (int j = 0; j < 4; ++j) {
          float ej = __expf(dt*Av[j]);
          h[j] = h[j]*ej + dtu*Bv[j];
          yp += h[j]*Cv[j];
        }
        float t1 = __uint_as_float((unsigned int)__builtin_amdgcn_mov_dpp(
                     (int)__float_as_uint(yp), 0xB1, 0xF, 0xF, true));
        float s1 = yp + t1;
        float t2 = __uint_as_float((unsigned int)__builtin_amdgcn_mov_dpp(
                     (int)__float_as_uint(s1), 0x4E, 0xF, 0xF, true));
        float ysum = s1 + t2;
        *(sUC + l*136 + d) = f2bf(ysum + u*dpv);
        (void)0;
      }
    }
  }
  __syncthreads();

  // ---- phase 6: yf = y * silu(z) from registers; dir-dependent YF layout.
  //      Each wave: its 16 tokens. dir 0/1: [n_all][l][d]; dir 2/3 transposed.
  {
    size_t rowbase;
    if (dir < 2)       rowbase = ((size_t)n_all*128 + st)*128;
    else if (dir == 2) rowbase = ((size_t)(512 + b*128 + st)*128 + r)*128;
    else               rowbase = ((size_t)(768 + b*128 + (127-st))*128 + r)*128;
    #pragma unroll
    for (int k = 0; k < 8; ++k) {
      const int dz = 16*k + quad*4;
      uint2 yv = *(const uint2*)(sUC + st*136 + dz);
      float y0 = __uint_as_float(yv.x << 16);
      float y1 = __uint_as_float(yv.x & 0xffff0000u);
      float y2 = __uint_as_float(yv.y << 16);
      float y3 = __uint_as_float(yv.y & 0xffff0000u);
      unsigned int z01 = zpk[k][0], z23 = zpk[k][1];
      float z0 = __uint_as_float(z01 << 16);
      float z1 = __uint_as_float(z01 & 0xffff0000u);
      float z2 = __uint_as_float(z23 << 16);
      float z3 = __uint_as_float(z23 & 0xffff0000u);
      uint2 ov;
      ov.x = pk2bf(y0*z0, y1*z1);
      ov.y = pk2bf(y2*z2, y3*z3);
      *(uint2*)(YF + rowbase + dz) = ov;
    }
  }
}

// ---------------------------------------------------------------- K3 (MFMA fuse + LN)
__global__ __launch_bounds__(256, 2) void k3_fuse(
    const unsigned short* __restrict__ YF, const unsigned short* __restrict__ MT16,
    const float* __restrict__ fuse_b, const float* __restrict__ ln_g,
    const float* __restrict__ ln_b, float* __restrict__ out)
{
  __shared__ __align__(16) unsigned short sYB[64*520];   // 66,560 B

  const int tid = threadIdx.x;
  const int blk = blockIdx.x;             // 512
  const int b = blk >> 8;
  const int rr2 = blk & 255;
  const int h = rr2 >> 1;
  const int w0 = (rr2 & 1) * 64;

  for (int f = tid*8; f < 32768; f += 2048) {
    int dirg = f >> 13;
    int rem = f & 8191;
    int tok = rem >> 7;
    int dd = rem & 127;
    int X = (dirg == 1) ? (127 - w0 - tok) : (w0 + tok);
    size_t base = ((size_t)(dirg*256 + b*128 + h)*128 + X)*128 + dd;
    *(uint4*)(sYB + tok*520 + dirg*128 + dd) = *(const uint4*)(YF + base);
  }
  __syncthreads();

  const int wave = tid >> 6;
  const int lane = tid & 63;
  const int m16 = lane & 15;
  const int quad = lane >> 4;
  const int tok = wave*16 + m16;

  short8 bfr[16];
  #pragma unroll
  for (int jt = 0; jt < 16; ++jt)
    bfr[jt] = *(const short8*)(sYB + tok*520 + jt*32 + quad*8);

  float facc[4][4];
  #pragma unroll
  for (int mt = 0; mt < 4; ++mt) {
    f32x4 acc = {0.f, 0.f, 0.f, 0.f};
    #pragma unroll
    for (int jt = 0; jt < 16; ++jt) {
      short8 af = *(const short8*)(MT16 + (size_t)(mt*16 + m16)*512 + jt*32 + quad*8);
      acc = __builtin_amdgcn_mfma_f32_16x16x32_bf16(af, bfr[jt], acc, 0, 0, 0);
    }
    facc[mt][0] = acc[0]; facc[mt][1] = acc[1]; facc[mt][2] = acc[2]; facc[mt][3] = acc[3];
  }

  float fv[16];
  float s1 = 0.f, s2 = 0.f;
  #pragma unroll
  for (int mt = 0; mt < 4; ++mt)
    #pragma unroll
    for (int rr = 0; rr < 4; ++rr) {
      int o = mt*16 + quad*4 + rr;
      float v = facc[mt][rr] + fuse_b[o];
      fv[mt*4 + rr] = v;
      s1 += v; s2 += v*v;
    }
  s1 += __shfl_xor(s1, 16, 64); s1 += __shfl_xor(s1, 32, 64);
  s2 += __shfl_xor(s2, 16, 64); s2 += __shfl_xor(s2, 32, 64);
  float mu = s1 * (1.f/64.f);
  float var = s2 * (1.f/64.f) - mu*mu;
  float rs = rsqrtf(var + 1e-5f);

  #pragma unroll
  for (int mt = 0; mt < 4; ++mt)
    #pragma unroll
    for (int rr = 0; rr < 4; ++rr) {
      int o = mt*16 + quad*4 + rr;
      float v = (fv[mt*4 + rr] - mu) * rs * ln_g[o] + ln_b[o];
      out[((size_t)(b*64 + o)*128 + h)*128 + (w0 + tok)] = siluf(v);
    }
}

// ---------------------------------------------------------------- host
extern "C" void kernel_launch(void* const* d_in, const int* in_sizes, int n_in,
                              void* d_out, int out_size, void* d_ws, size_t ws_size,
                              hipStream_t stream) {
  const float* x      = (const float*)d_in[0];
  const float* in_w   = (const float*)d_in[1];
  const float* conv_w = (const float*)d_in[2];
  const float* conv_b = (const float*)d_in[3];
  const float* xp_w   = (const float*)d_in[4];
  const float* dtp_w  = (const float*)d_in[5];
  const float* dtp_b  = (const float*)d_in[6];
  const float* A_log  = (const float*)d_in[7];
  const float* Dp     = (const float*)d_in[8];
  const float* out_w  = (const float*)d_in[9];
  const float* fuse_w = (const float*)d_in[10];
  const float* fuse_b = (const float*)d_in[11];
  const float* ln_g   = (const float*)d_in[12];
  const float* ln_b   = (const float*)d_in[13];
  float* out = (float*)d_out;

  // ws layout (BYTES):
  char* ws = (char*)d_ws;
  unsigned short* YF   = (unsigned short*)(ws);              // 33,554,432 (yf, dir-layouts)
  unsigned short* MT16 = (unsigned short*)(ws + 33554432);   //     65,536
  unsigned short* W16  = (unsigned short*)(ws + 33619968);   //    131,072
  unsigned short* XW16 = (unsigned short*)(ws + 33751040);   //     49,152
  unsigned short* XH   = (unsigned short*)(ws + 33800192);   //  4,194,304 (xhwc16)
  unsigned short* XWt  = (unsigned short*)(ws + 37994496);   //  4,194,304 (xwhc16)
  // total 42,188,800 B

  k0_prep<<<dim3(420), dim3(256), 0, stream>>>(out_w, fuse_w, in_w, xp_w, x,
                                               MT16, W16, XW16, XH, XWt);
  k1_front<<<dim3(1024), dim3(512), 0, stream>>>(XH, XWt, W16, XW16, conv_w, conv_b,
                                                 dtp_w, dtp_b, A_log, Dp, YF);
  k3_fuse<<<dim3(512), dim3(256), 0, stream>>>(YF, MT16, fuse_b, ln_g, ln_b, out);
}

// Round 5
// 203.489 us; speedup vs baseline: 1.3405x; 1.2203x over previous
//
#include <hip/hip_runtime.h>
#include <hip/hip_bf16.h>
#include <math.h>

// MambaBlock: 4-direction 2D selective scan + fuse + LN + SiLU
// B=2, H=W=128, D_MODEL=64, D_INNER=128, D_STATE=16, DT_RANK=4, D_CONV=4
//
// R16 = revert k1 to R13 (best measured 106.8us; R14 global-scan = 140us,
// R15 4thr/ch = 148us with +55% VALU work) + rework K3 for wave count.
// k0+k3 have been a constant ~99us across all rounds and never profiled
// (k1's 5 bench iters fill top-5). k3 was 256thr @ 2blk/CU = 8 waves/CU on
// a latency-bound scattered gather (32MB in 16B chunks). Now: 512thr @
// 2blk/CU = 16 waves/CU, grid 512 = exactly 1 resident round. Waves split
// (token-group x mt-half); LN gets a 1KB cross-wave LDS reduction.
//
//  K0: fold out_w*fuse_w -> MT16; in_w/xp_w -> bf16; x -> xhwc16 AND xwhc16.
//  K1 (53,248B LDS, 3 blk/CU): MFMA in-proj -> conv4+silu (packed) ->
//      MFMA xp-proj -> scan (2 thr/channel, packed f32, DPP pair-swap) ->
//      z-mul from regs -> YF (dir-dependent layout).
//  K3 (67,584B LDS, 2 blk/CU, 512 thr): gather, MFMA vs MT16, LN, SiLU.

typedef __attribute__((ext_vector_type(8))) short short8;
typedef __attribute__((ext_vector_type(4))) float f32x4;
typedef __attribute__((ext_vector_type(2))) float f32x2;

__device__ __forceinline__ f32x2 pk_mul(f32x2 a, f32x2 b) {
  f32x2 d;
  asm("v_pk_mul_f32 %0, %1, %2" : "=v"(d) : "v"(a), "v"(b));
  return d;
}
__device__ __forceinline__ f32x2 pk_fma(f32x2 a, f32x2 b, f32x2 c) {
  f32x2 d;
  asm("v_pk_fma_f32 %0, %1, %2, %3" : "=v"(d) : "v"(a), "v"(b), "v"(c));
  return d;
}

__device__ __forceinline__ unsigned int pk2bf(float a, float b) {
  __hip_bfloat162 h = __float22bfloat162_rn(make_float2(a, b));
  unsigned int u;
  __builtin_memcpy(&u, &h, 4);
  return u;
}
__device__ __forceinline__ unsigned short f2bf(float f) {
  __hip_bfloat16 h = __float2bfloat16(f);
  unsigned short s;
  __builtin_memcpy(&s, &h, 2);
  return s;
}
__device__ __forceinline__ float bf2f(unsigned short h) {
  return __uint_as_float(((unsigned int)h) << 16);
}
__device__ __forceinline__ float fastrcp(float x) { return __builtin_amdgcn_rcpf(x); }
__device__ __forceinline__ float siluf(float x) { return x * fastrcp(1.f + __expf(-x)); }

// ---------------------------------------------------------------- K0
// blk 0..127: fold -> MT16. 128..159: in_w -> W16. 160..163: xp_w -> XW16.
// blk 164..419: x[b][c][h][w] -> xhwc16[b][h][w][c] AND xwhc16[b][w][h][c].
__global__ void k0_prep(const float* __restrict__ out_w, const float* __restrict__ fuse_w,
                        const float* __restrict__ in_w, const float* __restrict__ xp_w,
                        const float* __restrict__ x,
                        unsigned short* __restrict__ MT16, unsigned short* __restrict__ W16,
                        unsigned short* __restrict__ XW16, unsigned short* __restrict__ XH,
                        unsigned short* __restrict__ XW) {
  __shared__ unsigned short sT[64*132];   // transpose stage (blk>=164 only)
  int blk = blockIdx.x;
  int tid = threadIdx.x;
  if (blk < 128) {
    int idx = blk * 256 + tid;   // 32768
    int d   = idx & 127;
    int o   = (idx >> 7) & 63;
    int dir = idx >> 13;
    float acc = 0.f;
    #pragma unroll 8
    for (int j = 0; j < 64; ++j)
      acc += out_w[(dir*64 + j)*128 + d] * fuse_w[o*256 + dir*64 + j];
    MT16[o*512 + dir*128 + d] = f2bf(acc);   // M^T layout [o][j=dir*128+d]
  } else if (blk < 160) {
    int t = (blk - 128) * 256 + tid;
    int base = t * 8;                        // 65536 total
    float4 v0 = *(const float4*)(in_w + base);
    float4 v1 = *(const float4*)(in_w + base + 4);
    uint4 pk;
    pk.x = pk2bf(v0.x, v0.y);
    pk.y = pk2bf(v0.z, v0.w);
    pk.z = pk2bf(v1.x, v1.y);
    pk.w = pk2bf(v1.z, v1.w);
    *(uint4*)(W16 + base) = pk;
  } else if (blk < 164) {
    int t = (blk - 160) * 256 + tid;        // 1024 threads
    for (int pid = t; pid < 4*48*128; pid += 1024) {
      int dir = pid / 6144;
      int rem = pid - dir*6144;
      int row = rem >> 7, c = rem & 127;
      XW16[pid] = (row < 36) ? f2bf(xp_w[dir*4608 + row*128 + c]) : (unsigned short)0;
    }
  } else {
    int idx = blk - 164;                    // 0..255
    int b = idx >> 7, h = idx & 127;
    for (int f = tid*4; f < 8192; f += 1024) {
      int c = f >> 7, w = f & 127;
      float4 v = *(const float4*)(x + (((size_t)(b*64 + c)*128 + h)*128 + w));
      sT[c*132 + w + 0] = f2bf(v.x);
      sT[c*132 + w + 1] = f2bf(v.y);
      sT[c*132 + w + 2] = f2bf(v.z);
      sT[c*132 + w + 3] = f2bf(v.w);
    }
    __syncthreads();
    for (int f = tid*8; f < 8192; f += 2048) {
      int w = f >> 6, c0 = f & 63;
      unsigned int pk[4];
      #pragma unroll
      for (int p = 0; p < 4; ++p) {
        unsigned int lo = sT[(c0 + p*2 + 0)*132 + w];
        unsigned int hi = sT[(c0 + p*2 + 1)*132 + w];
        pk[p] = lo | (hi << 16);
      }
      uint4 v; v.x = pk[0]; v.y = pk[1]; v.z = pk[2]; v.w = pk[3];
      *(uint4*)(XH + (((size_t)(b*128 + h)*128 + w)*64 + c0)) = v;
      *(uint4*)(XW + (((size_t)(b*128 + w)*128 + h)*64 + c0)) = v;
    }
  }
}

// ---------------------------------------------------------------- K1 (fused)
// LDS (53,248 B -> 3 blocks/CU):
//   sBCf @0     18432B fp32 [128 tok][36] (B cols 0..15, C cols 16..31) [ph4+]
//   sUC  @18432 34816B bf16 [128 tok][136]; cols 0..127 = u_pre -> uc -> y;
//                      cols 128..135 = dt-rank float4 [ph4+]
__global__ __launch_bounds__(256, 3) void k1_front(
    const unsigned short* __restrict__ XH, const unsigned short* __restrict__ XW,
    const unsigned short* __restrict__ W16, const unsigned short* __restrict__ XW16,
    const float* __restrict__ conv_w, const float* __restrict__ conv_b,
    const float* __restrict__ dtp_w, const float* __restrict__ dtp_b,
    const float* __restrict__ A_log, const float* __restrict__ Dp,
    unsigned short* __restrict__ YF)
{
  __shared__ __align__(16) char smem[53248];
  float* sBCf         = (float*)smem;                      // [128][36]  (ph4+)
  unsigned short* sUC = (unsigned short*)(smem + 18432);   // [128][136]

  const int tid = threadIdx.x;
  const int dir = blockIdx.x >> 8;
  const int n   = blockIdx.x & 255;
  const int b   = n >> 7;
  const int r   = n & 127;
  const int n_all = dir*256 + n;

  const unsigned short* xsrc = (dir < 2 ? XH : XW) + ((size_t)(b*128 + r)*128)*64;

  const int wave = tid >> 6;
  const int lane = tid & 63;
  const int m16 = lane & 15;
  const int quad = lane >> 4;
  const int tb0 = wave * 32;
  const int st0 = tb0 + m16;          // scan-order tokens owned (B-fragment rows)
  const int st1 = tb0 + 16 + m16;
  const int sp0 = (dir & 1) ? (127 - st0) : st0;   // spatial index in xsrc
  const int sp1 = (dir & 1) ? (127 - st1) : st1;

  unsigned int zpk[2][8][2];   // silu(z) bf16-packed: [tok-half][k][pair] (32 VGPRs)

  // ---- phase 2: MFMA in-projection. A=in_w (global bf16), B=x (global bf16). ----
  {
    short8 bfr[2][2];
    #pragma unroll
    for (int ks = 0; ks < 2; ++ks) {
      bfr[0][ks] = *(const short8*)(xsrc + sp0*64 + ks*32 + quad*8);
      bfr[1][ks] = *(const short8*)(xsrc + sp1*64 + ks*32 + quad*8);
    }
    const unsigned short* Wd = W16 + (size_t)dir * 16384;

    // u rows (rt 0..7)
    for (int rt = 0; rt < 8; ++rt) {
      short8 af[2];
      #pragma unroll
      for (int ks = 0; ks < 2; ++ks)
        af[ks] = *(const short8*)(Wd + (rt*16 + m16)*64 + ks*32 + quad*8);
      #pragma unroll
      for (int tt = 0; tt < 2; ++tt) {
        f32x4 acc = {0.f, 0.f, 0.f, 0.f};
        acc = __builtin_amdgcn_mfma_f32_16x16x32_bf16(af[0], bfr[tt][0], acc, 0, 0, 0);
        acc = __builtin_amdgcn_mfma_f32_16x16x32_bf16(af[1], bfr[tt][1], acc, 0, 0, 0);
        const int tok = tt ? st1 : st0;
        const int r0 = rt*16 + quad*4;
        uint2 u2;
        u2.x = pk2bf(acc[0], acc[1]);
        u2.y = pk2bf(acc[2], acc[3]);
        *(uint2*)(sUC + tok*136 + r0) = u2;
      }
    }
    // z rows (rt 8..15) -> registers
    #pragma unroll
    for (int k = 0; k < 8; ++k) {
      short8 af[2];
      #pragma unroll
      for (int ks = 0; ks < 2; ++ks)
        af[ks] = *(const short8*)(Wd + ((8+k)*16 + m16)*64 + ks*32 + quad*8);
      #pragma unroll
      for (int tt = 0; tt < 2; ++tt) {
        f32x4 acc = {0.f, 0.f, 0.f, 0.f};
        acc = __builtin_amdgcn_mfma_f32_16x16x32_bf16(af[0], bfr[tt][0], acc, 0, 0, 0);
        acc = __builtin_amdgcn_mfma_f32_16x16x32_bf16(af[1], bfr[tt][1], acc, 0, 0, 0);
        zpk[tt][k][0] = pk2bf(siluf(acc[0]), siluf(acc[1]));
        zpk[tt][k][1] = pk2bf(siluf(acc[2]), siluf(acc[3]));
      }
    }
  }
  __syncthreads();

  // ---- phase 3: causal conv-4 + silu in sUC (bf16). 4 chunks of 32 tokens;
  //      each thread interleaves 2 independent chunks, PACKED into f32x2 lanes
  //      (.x = chunk A, .y = chunk B) via v_pk_fma_f32.
  {
    const int d = tid & 127;
    const int half = tid >> 7;
    const int ca = half * 32;          // chunk A: 0 or 32
    const int cb2 = (half + 2) * 32;   // chunk B: 64 or 96
    const float* cw = conv_w + (size_t)(dir*128 + d)*4;
    const float c0w = cw[0], c1w = cw[1], c2w = cw[2], c3w = cw[3];
    const float cbv = conv_b[dir*128 + d];
    const f32x2 cw0v = {c0w, c0w}, cw1v = {c1w, c1w}, cw2v = {c2w, c2w}, cw3v = {c3w, c3w};
    const f32x2 cbv2 = {cbv, cbv};
    f32x2 A0 = { half ? bf2f(sUC[(ca-3)*136 + d]) : 0.f, bf2f(sUC[(cb2-3)*136 + d]) };
    f32x2 A1 = { half ? bf2f(sUC[(ca-2)*136 + d]) : 0.f, bf2f(sUC[(cb2-2)*136 + d]) };
    f32x2 A2 = { half ? bf2f(sUC[(ca-1)*136 + d]) : 0.f, bf2f(sUC[(cb2-1)*136 + d]) };
    __syncthreads();
    unsigned short* pa = sUC + ca*136 + d;
    unsigned short* pb = sUC + cb2*136 + d;
    for (int i = 0; i < 32; ++i) {
      f32x2 cur = { bf2f(*pa), bf2f(*pb) };
      f32x2 v = pk_fma(cw3v, cur,
                pk_fma(cw2v, A2,
                pk_fma(cw1v, A1,
                pk_fma(cw0v, A0, cbv2))));
      *pa = f2bf(siluf(v.x));
      *pb = f2bf(siluf(v.y));
      A0 = A1; A1 = A2; A2 = cur;
      pa += 136; pb += 136;
    }
  }
  __syncthreads();

  // ---- phase 4: MFMA xp-projection. A=xp_w (global bf16), B=uc (LDS sUC).
  //      dt rows -> sUC cols 128..135 (float4); B/C rows -> sBCf (fp32).
  {
    short8 bfr[2][4];
    #pragma unroll
    for (int tt = 0; tt < 2; ++tt)
      #pragma unroll
      for (int ks = 0; ks < 4; ++ks)
        bfr[tt][ks] = *(const short8*)(sUC + (tt ? st1 : st0)*136 + ks*32 + quad*8);

    const unsigned short* XWd = XW16 + (size_t)dir * (48*128);

    for (int rt = 0; rt < 3; ++rt) {
      short8 af[4];
      #pragma unroll
      for (int ks = 0; ks < 4; ++ks)
        af[ks] = *(const short8*)(XWd + (rt*16 + m16)*128 + ks*32 + quad*8);
      #pragma unroll
      for (int tt = 0; tt < 2; ++tt) {
        f32x4 acc = {0.f, 0.f, 0.f, 0.f};
        #pragma unroll
        for (int ks = 0; ks < 4; ++ks)
          acc = __builtin_amdgcn_mfma_f32_16x16x32_bf16(af[ks], bfr[tt][ks], acc, 0, 0, 0);
        const int tok = tt ? st1 : st0;
        const int r0 = rt*16 + quad*4;   // 0,4,...,44
        if (r0 == 0) {
          float4 v; v.x = acc[0]; v.y = acc[1]; v.z = acc[2]; v.w = acc[3];
          *(float4*)(smem + 18432 + tok*272 + 256) = v;      // sUC cols 128..135
        } else if (r0 < 36) {
          float4 v; v.x = acc[0]; v.y = acc[1]; v.z = acc[2]; v.w = acc[3];
          *(float4*)(sBCf + tok*36 + (r0 - 4)) = v;          // B: 0..15, C: 16..31
        }
      }
    }
  }
  __syncthreads();

  // ---- phase 5: selective scan, 2 threads/channel (8 states each). ----
  //      Packed f32 state math (v_pk_*), DPP quad-perm pair-swap, uncond store.
  {
    const int d = tid >> 1;
    const int p = tid & 1;
    const float* dwp = dtp_w + (size_t)(dir*128 + d) * 4;
    const float dw0 = dwp[0], dw1 = dwp[1], dw2 = dwp[2], dw3 = dwp[3];
    const float db = dtp_b[dir*128 + d];
    const float dpv = Dp[dir*128 + d];

    float Av[8];
    bool fast = true;
    #pragma unroll
    for (int j = 0; j < 8; ++j) {
      float a = -__expf(A_log[((size_t)(dir*128 + d))*16 + p*8 + j]);
      Av[j] = a;
      if (fabsf((-a) - (float)(p*8 + j + 1)) > 1e-3f) fast = false;
    }

    if (fast) {
      // E = exp(-softplus(dr)) = 1/(1+exp(dr)); e_j = E^(p*8+j+1).
      f32x2 h0 = {0.f, 0.f}, h1 = {0.f, 0.f}, h2v = {0.f, 0.f}, h3 = {0.f, 0.f};
      const char* qp = smem + 18432 + 256;             // dt float4, +272/tok
      const float* bp = sBCf + p*8;                    // B pairs, +36/tok
      const float* cp = sBCf + 16 + p*8;               // C pairs, +36/tok
      const unsigned short* up = sUC + d;              // u,  +136/tok
      unsigned short* yo = sUC + d;                    // y,  +136/tok
      for (int l = 0; l < 128; ++l) {
        float4 Q = *(const float4*)qp;
        f32x2 B01 = *(const f32x2*)(bp + 0), B23 = *(const f32x2*)(bp + 2);
        f32x2 B45 = *(const f32x2*)(bp + 4), B67 = *(const f32x2*)(bp + 6);
        f32x2 C01 = *(const f32x2*)(cp + 0), C23 = *(const f32x2*)(cp + 2);
        f32x2 C45 = *(const f32x2*)(cp + 4), C67 = *(const f32x2*)(cp + 6);
        float u = bf2f(*up);
        float dr = Q.x*dw0 + Q.y*dw1 + Q.z*dw2 + Q.w*dw3 + db;
        float te = __expf(dr);
        float dt = (dr > 20.f) ? dr : __logf(1.f + te);
        float dtu = dt * u;
        float E = fastrcp(1.f + te);
        float E2 = E*E, E4 = E2*E2, E8 = E4*E4;
        float eb = p ? E8 : 1.f;
        f32x2 P0 = {E*eb, E2*eb};
        f32x2 E2v = {E2, E2};
        f32x2 P1 = pk_mul(P0, E2v);
        f32x2 P2 = pk_mul(P1, E2v);
        f32x2 P3 = pk_mul(P2, E2v);
        f32x2 du = {dtu, dtu};
        h0  = pk_fma(h0,  P0, pk_mul(du, B01));
        h1  = pk_fma(h1,  P1, pk_mul(du, B23));
        h2v = pk_fma(h2v, P2, pk_mul(du, B45));
        h3  = pk_fma(h3,  P3, pk_mul(du, B67));
        f32x2 ya = pk_mul(h0, C01);
        f32x2 yb = pk_mul(h1, C23);
        ya = pk_fma(h2v, C45, ya);
        yb = pk_fma(h3,  C67, yb);
        float ypar = (ya.x + ya.y) + (yb.x + yb.y);
        // pair-swap within quad: lane^1 (p0<->p1), 1 VALU via DPP quad_perm
        float ot = __uint_as_float((unsigned int)__builtin_amdgcn_mov_dpp(
                     (int)__float_as_uint(ypar), 0xB1, 0xF, 0xF, true));
        float ysum = ypar + ot;                  // bit-identical on both lanes
        *yo = f2bf(ysum + u*dpv);                // same value, same addr: benign
        qp += 272; bp += 36; cp += 36; up += 136; yo += 136;
      }
    } else {
      float h[8];
      #pragma unroll
      for (int j = 0; j < 8; ++j) h[j] = 0.f;
      for (int l = 0; l < 128; ++l) {
        float4 Q = *(const float4*)(smem + 18432 + l*272 + 256);
        float4 b0 = *(const float4*)(sBCf + l*36 + p*8);
        float4 b1 = *(const float4*)(sBCf + l*36 + p*8 + 4);
        float4 c0 = *(const float4*)(sBCf + l*36 + 16 + p*8);
        float4 c1 = *(const float4*)(sBCf + l*36 + 16 + p*8 + 4);
        float Bv[8] = {b0.x,b0.y,b0.z,b0.w, b1.x,b1.y,b1.z,b1.w};
        float Cv[8] = {c0.x,c0.y,c0.z,c0.w, c1.x,c1.y,c1.z,c1.w};
        float u = bf2f(sUC[l*136 + d]);
        float dr = Q.x*dw0 + Q.y*dw1 + Q.z*dw2 + Q.w*dw3 + db;
        float te = __expf(dr);
        float dt = (dr > 20.f) ? dr : __logf(1.f + te);
        float dtu = dt * u;
        float yp = 0.f;
        #pragma unroll
        for (int j = 0; j < 8; ++j) {
          float ej = __expf(dt*Av[j]);
          h[j] = h[j]*ej + dtu*Bv[j];
          yp += h[j]*Cv[j];
        }
        float ot = __uint_as_float((unsigned int)__builtin_amdgcn_mov_dpp(
                     (int)__float_as_uint(yp), 0xB1, 0xF, 0xF, true));
        float ysum = yp + ot;
        if (p == 0) sUC[l*136 + d] = f2bf(ysum + u*dpv);
      }
    }
  }
  __syncthreads();

  // ---- phase 6: yf = y * silu(z) from registers; dir-dependent YF layout.
  //      dir 0/1: [n_all][l][d]; dir 2/3: transposed [dir][b*128+h][w][d].
  #pragma unroll
  for (int tt = 0; tt < 2; ++tt) {
    const int st = tt ? st1 : st0;
    size_t rowbase;
    if (dir < 2)       rowbase = ((size_t)n_all*128 + st)*128;
    else if (dir == 2) rowbase = ((size_t)(512 + b*128 + st)*128 + r)*128;
    else               rowbase = ((size_t)(768 + b*128 + (127-st))*128 + r)*128;
    #pragma unroll
    for (int k = 0; k < 8; ++k) {
      const int dz = 16*k + quad*4;
      uint2 yv = *(const uint2*)(sUC + st*136 + dz);
      float y0 = __uint_as_float(yv.x << 16);
      float y1 = __uint_as_float(yv.x & 0xffff0000u);
      float y2 = __uint_as_float(yv.y << 16);
      float y3 = __uint_as_float(yv.y & 0xffff0000u);
      unsigned int z01 = zpk[tt][k][0], z23 = zpk[tt][k][1];
      float z0 = __uint_as_float(z01 << 16);
      float z1 = __uint_as_float(z01 & 0xffff0000u);
      float z2 = __uint_as_float(z23 << 16);
      float z3 = __uint_as_float(z23 & 0xffff0000u);
      uint2 ov;
      ov.x = pk2bf(y0*z0, y1*z1);
      ov.y = pk2bf(y2*z2, y3*z3);
      *(uint2*)(YF + rowbase + dz) = ov;
    }
  }
}

// ---------------------------------------------------------------- K3 (MFMA fuse + LN)
// 512 threads, 2 blocks/CU -> 16 waves/CU (was 8). Grid 512 = 1 resident round.
// Wave w: token group (w&3)*16, mt-half (w>>2). LN partial sums cross the
// mt-halves via a 1KB LDS buffer + one barrier.
__global__ __launch_bounds__(512, 2) void k3_fuse(
    const unsigned short* __restrict__ YF, const unsigned short* __restrict__ MT16,
    const float* __restrict__ fuse_b, const float* __restrict__ ln_g,
    const float* __restrict__ ln_b, float* __restrict__ out)
{
  __shared__ __align__(16) unsigned short sYB[64*520];   // 66,560 B
  __shared__ float sLN[2][64][2];                        //  1,024 B

  const int tid = threadIdx.x;
  const int blk = blockIdx.x;             // 512
  const int b = blk >> 8;
  const int rr2 = blk & 255;
  const int h = rr2 >> 1;
  const int w0 = (rr2 & 1) * 64;

  for (int f = tid*8; f < 32768; f += 4096) {
    int dirg = f >> 13;
    int rem = f & 8191;
    int tok = rem >> 7;
    int dd = rem & 127;
    int X = (dirg == 1) ? (127 - w0 - tok) : (w0 + tok);
    size_t base = ((size_t)(dirg*256 + b*128 + h)*128 + X)*128 + dd;
    *(uint4*)(sYB + tok*520 + dirg*128 + dd) = *(const uint4*)(YF + base);
  }
  __syncthreads();

  const int wave = tid >> 6;     // 0..7
  const int lane = tid & 63;
  const int m16 = lane & 15;
  const int quad = lane >> 4;
  const int tg   = wave & 3;     // token group
  const int mh   = wave >> 2;    // mt half: 0 -> mt{0,1}, 1 -> mt{2,3}
  const int tok  = tg*16 + m16;

  short8 bfr[16];
  #pragma unroll
  for (int jt = 0; jt < 16; ++jt)
    bfr[jt] = *(const short8*)(sYB + tok*520 + jt*32 + quad*8);

  float facc[2][4];
  #pragma unroll
  for (int mi = 0; mi < 2; ++mi) {
    const int mt = mh*2 + mi;
    f32x4 acc = {0.f, 0.f, 0.f, 0.f};
    #pragma unroll
    for (int jt = 0; jt < 16; ++jt) {
      short8 af = *(const short8*)(MT16 + (size_t)(mt*16 + m16)*512 + jt*32 + quad*8);
      acc = __builtin_amdgcn_mfma_f32_16x16x32_bf16(af, bfr[jt], acc, 0, 0, 0);
    }
    facc[mi][0] = acc[0]; facc[mi][1] = acc[1]; facc[mi][2] = acc[2]; facc[mi][3] = acc[3];
  }

  float fv[8];
  float s1 = 0.f, s2 = 0.f;
  #pragma unroll
  for (int mi = 0; mi < 2; ++mi)
    #pragma unroll
    for (int rr = 0; rr < 4; ++rr) {
      int o = (mh*2 + mi)*16 + quad*4 + rr;
      float v = facc[mi][rr] + fuse_b[o];
      fv[mi*4 + rr] = v;
      s1 += v; s2 += v*v;
    }
  // within-wave: combine the 4 quads -> per-token partial over this wave's 32 o
  s1 += __shfl_xor(s1, 16, 64); s1 += __shfl_xor(s1, 32, 64);
  s2 += __shfl_xor(s2, 16, 64); s2 += __shfl_xor(s2, 32, 64);
  if (lane < 16) {
    sLN[mh][tok][0] = s1;
    sLN[mh][tok][1] = s2;
  }
  __syncthreads();
  float t1 = s1 + sLN[1 - mh][tok][0];
  float t2 = s2 + sLN[1 - mh][tok][1];
  float mu = t1 * (1.f/64.f);
  float var = t2 * (1.f/64.f) - mu*mu;
  float rs = rsqrtf(var + 1e-5f);

  #pragma unroll
  for (int mi = 0; mi < 2; ++mi)
    #pragma unroll
    for (int rr = 0; rr < 4; ++rr) {
      int o = (mh*2 + mi)*16 + quad*4 + rr;
      float v = (fv[mi*4 + rr] - mu) * rs * ln_g[o] + ln_b[o];
      out[((size_t)(b*64 + o)*128 + h)*128 + (w0 + tok)] = siluf(v);
    }
}

// ---------------------------------------------------------------- host
extern "C" void kernel_launch(void* const* d_in, const int* in_sizes, int n_in,
                              void* d_out, int out_size, void* d_ws, size_t ws_size,
                              hipStream_t stream) {
  const float* x      = (const float*)d_in[0];
  const float* in_w   = (const float*)d_in[1];
  const float* conv_w = (const float*)d_in[2];
  const float* conv_b = (const float*)d_in[3];
  const float* xp_w   = (const float*)d_in[4];
  const float* dtp_w  = (const float*)d_in[5];
  const float* dtp_b  = (const float*)d_in[6];
  const float* A_log  = (const float*)d_in[7];
  const float* Dp     = (const float*)d_in[8];
  const float* out_w  = (const float*)d_in[9];
  const float* fuse_w = (const float*)d_in[10];
  const float* fuse_b = (const float*)d_in[11];
  const float* ln_g   = (const float*)d_in[12];
  const float* ln_b   = (const float*)d_in[13];
  float* out = (float*)d_out;

  // ws layout (BYTES):
  char* ws = (char*)d_ws;
  unsigned short* YF   = (unsigned short*)(ws);              // 33,554,432 (yf, dir-layouts)
  unsigned short* MT16 = (unsigned short*)(ws + 33554432);   //     65,536
  unsigned short* W16  = (unsigned short*)(ws + 33619968);   //    131,072
  unsigned short* XW16 = (unsigned short*)(ws + 33751040);   //     49,152
  unsigned short* XH   = (unsigned short*)(ws + 33800192);   //  4,194,304 (xhwc16)
  unsigned short* XWt  = (unsigned short*)(ws + 37994496);   //  4,194,304 (xwhc16)
  // total 42,188,800 B

  k0_prep<<<dim3(420), dim3(256), 0, stream>>>(out_w, fuse_w, in_w, xp_w, x,
                                               MT16, W16, XW16, XH, XWt);
  k1_front<<<dim3(1024), dim3(256), 0, stream>>>(XH, XWt, W16, XW16, conv_w, conv_b,
                                                 dtp_w, dtp_b, A_log, Dp, YF);
  k3_fuse<<<dim3(512), dim3(512), 0, stream>>>(YF, MT16, fuse_b, ln_g, ln_b, out);
}